// Round 10
// baseline (158.906 us; speedup 1.0000x reference)
//
#include <hip/hip_runtime.h>

typedef short bf16x8 __attribute__((ext_vector_type(8)));
typedef float f32x4 __attribute__((ext_vector_type(4)));
typedef unsigned short u16;

#define NNODE 196608
#define FF 32
#define COLS 256   // UP * OUT_FEATURES
#define KTOT 288   // KK * FF
#define WELEMS (COLS * KTOT)   // 73728 elems = 144 KB bf16
#define TPB 6                  // tiles per block (1536 / 256)

__device__ __forceinline__ u16 f2bf(float f) {
    unsigned u = __builtin_bit_cast(unsigned, f);
    return (u16)((u + 0x7fffu + ((u >> 16) & 1u)) >> 16);  // RTNE
}

// prep 1: x (2,N,32) f32 -> xb2 bf16 INTERLEAVED: xb2[node][0:32]=t0 feats,
// xb2[node][32:64]=t1 feats -> one 128-B line per node (gather = 1 line).
__global__ void cvt_x(const float* __restrict__ x, u16* __restrict__ xb2, int n8) {
    int i = blockIdx.x * blockDim.x + threadIdx.x;
    if (i >= n8) return;
    int og   = i * 8;           // output element index (u16 units)
    int node = og >> 6;
    int rem  = og & 63;
    int s    = rem >> 5;        // t-slice
    int f0   = rem & 31;        // feature start (0,8,16,24)
    const float* src = x + ((size_t)s * NNODE + node) * FF + f0;
    f32x4 v0 = *(const f32x4*)src;
    f32x4 v1 = *(const f32x4*)(src + 4);
    union { u16 h[8]; bf16x8 v; } r;
    #pragma unroll
    for (int j = 0; j < 4; ++j) r.h[j] = f2bf(v0[j]);
    #pragma unroll
    for (int j = 0; j < 4; ++j) r.h[4 + j] = f2bf(v1[j]);
    *((bf16x8*)xb2 + i) = r.v;
}

// prep 2: W (K,F,UP,O) f32 -> Wt bf16, MFMA fragment-linear:
// Wt[f*512 + lane*8 + e] = W[kf][c], f = kk*16+ct, c = ct*16+(lane&15),
// kf = kk*32 + (lane>>4)*8 + e. Wave ds_read_b128 of a frag: lane-linear.
__global__ void cvt_w(const float* __restrict__ W, u16* __restrict__ Wt) {
    int gid = blockIdx.x * 256 + threadIdx.x;   // 73728 total
    int f      = gid >> 9;
    int within = gid & 511;
    int lane   = within >> 3;
    int e      = within & 7;
    int kk = f >> 4, ct = f & 15;
    int cl = lane & 15, q = lane >> 4;
    int c  = ct * 16 + cl;
    int kf = kk * 32 + q * 8 + e;
    Wt[gid] = f2bf(W[(size_t)kf * COLS + c]);
}

// main: grid 256 (1 blk/CU via 145 KB LDS), 512 thr = 8 waves, static 6
// tiles/blk. Wave = 16 nodes x 2 t-slices x 256 cols.
// KEY (R10): vmcnt retires IN ISSUE ORDER, so a gather issued after stores
// and consumed during the drain window forces a full store-backlog drain
// (R8's hidden serializer). Fix: prefetch ALL 18 gathers (9k x 2t) of tile
// tt+1 BEFORE tile tt's stores; the whole next kk-loop consumes only
// pre-store gathers -> stores drain lazily under a full tile of compute.
// No barriers after prologue (waves free-run -> phase-staggered overlap).
// R6/R7 lesson: seam state is ONLY g0/g1/idx (the same regs the loop uses).
__global__ __launch_bounds__(512, 2) void updown_main(
    const u16* __restrict__ xb2, const u16* __restrict__ Wt,
    const int* __restrict__ adjc, const float* __restrict__ bias,
    float* __restrict__ out)
{
    __shared__ __align__(16) u16 wlds[WELEMS];   // 144 KB, read-only after load
    __shared__ __align__(16) float blds[COLS];   // 1 KB bias

    const int tid = threadIdx.x;

    #pragma unroll
    for (int i = 0; i < 18; ++i)
        *(bf16x8*)(wlds + i * 4096 + tid * 8) =
            *(const bf16x8*)(Wt + i * 4096 + tid * 8);
    if (tid < 64) ((f32x4*)blds)[tid] = ((const f32x4*)bias)[tid];
    __syncthreads();   // the only barrier

    const int w    = tid >> 6;
    const int lane = tid & 63;
    const int l15  = lane & 15;
    const int q    = lane >> 4;
    const u16* wbase = wlds + lane * 8;   // + kk*8192 + ct*512
    const float* bb  = blds + q * 4;      // + ct*16

    const int node0 = blockIdx.x * (TPB * 128) + w * 16 + l15;

    // tile-0 prologue: all 9 idx, then all 18 gathers in flight
    bf16x8 g0[9], g1[9];
    {
        const int* arow = adjc + (size_t)node0 * 9;
        int idxA[9];
        #pragma unroll
        for (int k = 0; k < 9; ++k) idxA[k] = arow[k];
        #pragma unroll
        for (int k = 0; k < 9; ++k) {
            const u16* p = xb2 + (size_t)idxA[k] * 64 + q * 8;
            g0[k] = *(const bf16x8*)p;
            g1[k] = *(const bf16x8*)(p + 32);
        }
    }

    for (int tt = 0; tt < TPB; ++tt) {
        const int node = node0 + tt * 128;

        // acc init = bias (LDS broadcast reads -> lgkm, not the vmcnt FIFO)
        f32x4 acc0[16], acc1[16];
        #pragma unroll
        for (int ct = 0; ct < 16; ++ct) {
            f32x4 bq = *(const f32x4*)(bb + ct * 16);
            acc0[ct] = bq;
            acc1[ct] = bq;
        }

        // next tile's idx loads (independent; scheduler may hoist freely —
        // they are YOUNGER than g[], so consuming g[] never waits on them)
        int idxN[9];
        if (tt < TPB - 1) {
            const int* arow2 = adjc + (size_t)(node + 128) * 9;
            #pragma unroll
            for (int k = 0; k < 9; ++k) idxN[k] = arow2[k];
        }

        // K-loop: pure LDS + MFMA; consumes only pre-issued gathers
        #pragma unroll
        for (int kk = 0; kk < 9; ++kk) {
            const u16* wk = wbase + kk * 8192;
            #pragma unroll
            for (int ct = 0; ct < 16; ++ct) {
                bf16x8 af = *(const bf16x8*)(wk + ct * 512);
                acc0[ct] = __builtin_amdgcn_mfma_f32_16x16x32_bf16(af, g0[kk], acc0[ct], 0, 0, 0);
                acc1[ct] = __builtin_amdgcn_mfma_f32_16x16x32_bf16(af, g1[kk], acc1[ct], 0, 0, 0);
            }
        }

        // SEAM: issue next tile's 18 gathers FIRST (older than stores) ...
        if (tt < TPB - 1) {
            #pragma unroll
            for (int k = 0; k < 9; ++k) {
                const u16* p = xb2 + (size_t)idxN[k] * 64 + q * 8;
                g0[k] = *(const bf16x8*)p;
                g1[k] = *(const bf16x8*)(p + 32);
            }
        }
        __builtin_amdgcn_sched_barrier(0);   // pin: gathers precede stores

        // ... THEN stores; they drain lazily under the next tile's compute
        float* o0 = out + (size_t)node * COLS + q * 4;
        float* o1 = o0 + (size_t)NNODE * COLS;
        #pragma unroll
        for (int ct = 0; ct < 16; ++ct) {
            *(f32x4*)(o0 + ct * 16) = acc0[ct];
            *(f32x4*)(o1 + ct * 16) = acc1[ct];
        }
    }
}

extern "C" void kernel_launch(void* const* d_in, const int* in_sizes, int n_in,
                              void* d_out, int out_size, void* d_ws, size_t ws_size,
                              hipStream_t stream) {
    const float* x    = (const float*)d_in[0];
    const int*   adjc = (const int*)d_in[1];
    const float* W    = (const float*)d_in[2];
    const float* b    = (const float*)d_in[3];
    float* out = (float*)d_out;

    u16* xb2 = (u16*)d_ws;                           // 196608*64 bf16 = 25.2 MB
    u16* Wt  = xb2 + (size_t)NNODE * 64;             // 73728 bf16 = 144 KB

    cvt_x<<<dim3(6144), dim3(256), 0, stream>>>(x, xb2, 1572864);
    cvt_w<<<dim3(288), dim3(256), 0, stream>>>(W, Wt);
    updown_main<<<dim3(256), dim3(512), 0, stream>>>(xb2, Wt, adjc, b, out);
}